// Round 1
// baseline (761.149 us; speedup 1.0000x reference)
//
#include <hip/hip_runtime.h>
#include <hip/hip_bf16.h>

typedef __bf16 bf16x8 __attribute__((ext_vector_type(8)));
typedef float f32x4 __attribute__((ext_vector_type(4)));

#define LOG2E      1.4426950408889634f
#define SELU_SCALE 1.0507009873554805f
#define SELU_ALPHA 1.6732632423543772f
#define HPAD 136   // 128 + 8 bf16 pad (272B rows, 16B-aligned, conflict-light)
#define PPAD 129   // fp32 pooling rows

__device__ __forceinline__ float fexp2(float x){ return __builtin_amdgcn_exp2f(x); }
__device__ __forceinline__ float frcp (float x){ return __builtin_amdgcn_rcpf(x); }
__device__ __forceinline__ float tanh_fast(float x){
  return 1.0f - 2.0f * frcp(fexp2(x * (2.0f * LOG2E)) + 1.0f);
}
__device__ __forceinline__ float sigmoid_fast(float x){
  return frcp(1.0f + fexp2(-LOG2E * x));
}
__device__ __forceinline__ float selu_fast(float x){
  float e = SELU_ALPHA * (fexp2(LOG2E * x) - 1.0f);
  return SELU_SCALE * (x > 0.0f ? x : e);
}
__device__ __forceinline__ unsigned short f2bf(float f){
  unsigned u = __builtin_bit_cast(unsigned, f);
  u += 0x7fffu + ((u >> 16) & 1u);          // round-to-nearest-even
  return (unsigned short)(u >> 16);
}
__device__ __forceinline__ bf16x8 pack8(float4 a, float4 b){
  union { bf16x8 v; unsigned short s[8]; } u;
  u.s[0]=f2bf(a.x); u.s[1]=f2bf(a.y); u.s[2]=f2bf(a.z); u.s[3]=f2bf(a.w);
  u.s[4]=f2bf(b.x); u.s[5]=f2bf(b.y); u.s[6]=f2bf(b.z); u.s[7]=f2bf(b.w);
  return u.v;
}
__device__ __forceinline__ int imin(int a, int b){ return a < b ? a : b; }

// exclusive prefix scan of n_node -> offs[0..B], one block of 256 threads
__global__ __launch_bounds__(256) void scan_kernel(const int* __restrict__ n_node,
                                                   int* __restrict__ offs, int B){
  __shared__ int part[256];
  const int t = threadIdx.x;
  const int chunk = (B + 255) / 256;
  int s = 0;
  for (int i = 0; i < chunk; ++i){ int idx = t * chunk + i; if (idx < B) s += n_node[idx]; }
  part[t] = s;
  __syncthreads();
  if (t == 0){
    int run = 0;
    for (int i = 0; i < 256; ++i){ int v = part[i]; part[i] = run; run += v; }
    offs[B] = run;
  }
  __syncthreads();
  int run = part[t];
  for (int i = 0; i < chunk; ++i){
    int idx = t * chunk + i;
    if (idx < B){ offs[idx] = run; run += n_node[idx]; }
  }
}

// transpose + fold + bf16-convert the four node-MLP weight matrices
__global__ __launch_bounds__(256) void prep_weights(
    const float* __restrict__ i1w, const float* __restrict__ j1w,
    const float* __restrict__ i2w, const float* __restrict__ j2w,
    unsigned short* __restrict__ wi1t, unsigned short* __restrict__ wj1t,
    unsigned short* __restrict__ wi2t, unsigned short* __restrict__ wj2t){
  int id = blockIdx.x * 256 + threadIdx.x;
  if (id < 8192){
    int n = id >> 6, k = id & 63;
    float v = i1w[k * 128 + n];
    if (k < 2) v += i1w[(64 + k) * 128 + n];     // fold hx dup-columns
    wi1t[n * 64 + k] = f2bf(v);
  } else if (id < 16384){
    int m = id - 8192; int n = m >> 6, k = m & 63;
    float v = j1w[k * 128 + n];
    if (k < 2) v += j1w[(64 + k) * 128 + n];
    wj1t[n * 64 + k] = f2bf(v);
  } else if (id < 32768){
    int m = id - 16384; int n = m >> 7, k = m & 127;
    wi2t[n * 128 + k] = f2bf(i2w[k * 128 + n]);
  } else if (id < 49152){
    int m = id - 32768; int n = m >> 7, k = m & 127;
    wj2t[n * 128 + k] = f2bf(j2w[k * 128 + n]);
  }
}

__device__ __forceinline__ int find_graph(const int* __restrict__ offs, int B, int n){
  int lo = 0, hi = B - 1;                 // largest g with offs[g] <= n
  while (lo < hi){
    int mid = (lo + hi + 1) >> 1;
    if (offs[mid] <= n) lo = mid; else hi = mid - 1;
  }
  return lo;
}

// one WG = 64 nodes, 256 threads (4 waves). Fused: both branches, 2 layers,
// gate, mask, segment pooling via atomics.
__global__ __launch_bounds__(256) void fused_node_kernel(
    const float* __restrict__ nodes, const float* __restrict__ node_mask,
    const unsigned short* __restrict__ wi1t, const unsigned short* __restrict__ wj1t,
    const unsigned short* __restrict__ wi2t, const unsigned short* __restrict__ wj2t,
    const float* __restrict__ i1b, const float* __restrict__ i2b,
    const float* __restrict__ j1b, const float* __restrict__ j2b,
    const int* __restrict__ offs, float* __restrict__ pooled, int N, int B){

  // LDS: H (64x136 bf16 = 17408B) overlaid by P (64x129 f32 = 33024B); then mask+gid
  __shared__ __align__(16) unsigned char smem[33024 + 256 + 256];
  unsigned short* Hs   = (unsigned short*)smem;          // [64][HPAD]
  float*          P    = (float*)smem;                   // [64][PPAD]
  float*          maskl= (float*)(smem + 33024);         // [64]
  int*            gidl = (int*)(smem + 33024 + 256);     // [64]

  const int t   = threadIdx.x;
  const int wv  = t >> 6;          // wave 0..3 -> cols [wv*32, wv*32+32)
  const int l   = t & 63;
  const int lm  = l & 15;          // m/n within 16x16 tile
  const int lk8 = (l >> 4) * 8;    // k-octet start
  const int n0  = blockIdx.x * 64;

  if (t < 64){
    int n = n0 + t;
    maskl[t] = (n < N) ? node_mask[n] : 0.0f;
    gidl[t]  = find_graph(offs, B, imin(n, N - 1));
  }

  // A fragments (nodes, fp32 -> bf16), persistent for both branches
  bf16x8 af[4][2];
  #pragma unroll
  for (int rt = 0; rt < 4; ++rt){
    int row = n0 + rt * 16 + lm; if (row >= N) row = N - 1;
    const float* p = nodes + (size_t)row * 64;
    #pragma unroll
    for (int kb = 0; kb < 2; ++kb){
      const float4* q = (const float4*)(p + kb * 32 + lk8);
      af[rt][kb] = pack8(q[0], q[1]);
    }
  }

  const f32x4 zero4 = {0.f, 0.f, 0.f, 0.f};
  float gate[2][4][4];

  #pragma unroll
  for (int br = 0; br < 2; ++br){
    const unsigned short* w1 = (br == 0) ? wi1t : wj1t;
    const unsigned short* w2 = (br == 0) ? wi2t : wj2t;
    const float*          b1 = (br == 0) ? i1b  : j1b;
    const float*          b2 = (br == 0) ? i2b  : j2b;

    // ---- layer 1: [64x64] @ [64x128] ----
    f32x4 acc[2][4];
    #pragma unroll
    for (int c = 0; c < 2; ++c)
      #pragma unroll
      for (int rt = 0; rt < 4; ++rt) acc[c][rt] = zero4;

    #pragma unroll
    for (int kb = 0; kb < 2; ++kb){
      bf16x8 bf0 = *(const bf16x8*)(w1 + ((wv*2+0)*16 + lm) * 64 + kb*32 + lk8);
      bf16x8 bf1 = *(const bf16x8*)(w1 + ((wv*2+1)*16 + lm) * 64 + kb*32 + lk8);
      #pragma unroll
      for (int rt = 0; rt < 4; ++rt){
        acc[0][rt] = __builtin_amdgcn_mfma_f32_16x16x32_bf16(af[rt][kb], bf0, acc[0][rt], 0,0,0);
        acc[1][rt] = __builtin_amdgcn_mfma_f32_16x16x32_bf16(af[rt][kb], bf1, acc[1][rt], 0,0,0);
      }
    }

    // bias + activation -> H (bf16, row-major padded)
    float bv0 = b1[(wv*2+0)*16 + lm];
    float bv1 = b1[(wv*2+1)*16 + lm];
    #pragma unroll
    for (int c = 0; c < 2; ++c){
      int col = (wv*2+c)*16 + lm;
      float bv = c ? bv1 : bv0;
      #pragma unroll
      for (int rt = 0; rt < 4; ++rt)
        #pragma unroll
        for (int r = 0; r < 4; ++r){
          float v = acc[c][rt][r] + bv;
          v = (br == 0) ? tanh_fast(v) : selu_fast(v);
          int row = rt*16 + (l >> 4)*4 + r;
          Hs[row * HPAD + col] = f2bf(v);
        }
    }
    __syncthreads();   // H complete

    // ---- layer 2: [64x128] @ [128x128] ----
    f32x4 acc2[2][4];
    #pragma unroll
    for (int c = 0; c < 2; ++c)
      #pragma unroll
      for (int rt = 0; rt < 4; ++rt) acc2[c][rt] = zero4;

    #pragma unroll
    for (int kb = 0; kb < 4; ++kb){
      bf16x8 bf0 = *(const bf16x8*)(w2 + ((wv*2+0)*16 + lm) * 128 + kb*32 + lk8);
      bf16x8 bf1 = *(const bf16x8*)(w2 + ((wv*2+1)*16 + lm) * 128 + kb*32 + lk8);
      #pragma unroll
      for (int rt = 0; rt < 4; ++rt){
        bf16x8 a = *(const bf16x8*)(Hs + (rt*16 + lm) * HPAD + kb*32 + lk8);
        acc2[0][rt] = __builtin_amdgcn_mfma_f32_16x16x32_bf16(a, bf0, acc2[0][rt], 0,0,0);
        acc2[1][rt] = __builtin_amdgcn_mfma_f32_16x16x32_bf16(a, bf1, acc2[1][rt], 0,0,0);
      }
    }

    float c2v0 = b2[(wv*2+0)*16 + lm];
    float c2v1 = b2[(wv*2+1)*16 + lm];

    if (br == 0){
      #pragma unroll
      for (int c = 0; c < 2; ++c){
        float bv = c ? c2v1 : c2v0;
        #pragma unroll
        for (int rt = 0; rt < 4; ++rt)
          #pragma unroll
          for (int r = 0; r < 4; ++r)
            gate[c][rt][r] = sigmoid_fast(acc2[c][rt][r] + bv);
      }
      __syncthreads();  // all H reads done before branch-j overwrites H
    } else {
      float rr[2][4][4];
      #pragma unroll
      for (int c = 0; c < 2; ++c){
        float bv = c ? c2v1 : c2v0;
        #pragma unroll
        for (int rt = 0; rt < 4; ++rt)
          #pragma unroll
          for (int r = 0; r < 4; ++r)
            rr[c][rt][r] = gate[c][rt][r] * (acc2[c][rt][r] + bv);
      }
      __syncthreads();  // all H reads done; P may overlay H now
      #pragma unroll
      for (int c = 0; c < 2; ++c){
        int col = (wv*2+c)*16 + lm;
        #pragma unroll
        for (int rt = 0; rt < 4; ++rt)
          #pragma unroll
          for (int r = 0; r < 4; ++r){
            int row = rt*16 + (l >> 4)*4 + r;
            P[row * PPAD + col] = rr[c][rt][r];
          }
      }
      __syncthreads();

      // ---- pooling: per-column partial sums per graph segment ----
      int c    = t & 127;
      int half = t >> 7;
      int r0 = half * 32;
      int r1 = imin(r0 + 32, imin(64, N - n0));
      if (r0 < r1){
        float part = 0.0f;
        int g = gidl[r0];
        for (int row = r0; row < r1; ++row){
          int gr = gidl[row];
          if (gr != g){
            if (part != 0.0f) atomicAdd(&pooled[g * 128 + c], part);
            part = 0.0f; g = gr;
          }
          part += P[row * PPAD + c] * maskl[row];
        }
        if (part != 0.0f) atomicAdd(&pooled[g * 128 + c], part);
      }
    }
  }
}

// head: out[g] = selu(pooled[g] @ h1_w + h1_b) @ h2_w + h2_b   (fp32)
__global__ __launch_bounds__(128) void head_kernel(
    const float* __restrict__ pooled, const float* __restrict__ h1w,
    const float* __restrict__ h1b, const float* __restrict__ h2w,
    const float* __restrict__ h2b, float* __restrict__ out){
  __shared__ float pg[128];
  __shared__ float red[64];
  const int g = blockIdx.x, t = threadIdx.x;
  pg[t] = pooled[g * 128 + t];
  __syncthreads();
  float acc = h1b[t];
  #pragma unroll 8
  for (int k = 0; k < 128; ++k) acc += pg[k] * h1w[k * 128 + t];
  float s = selu_fast(acc) * h2w[t];
  if (t >= 64) red[t - 64] = s;
  __syncthreads();
  if (t < 64){
    float v = s + red[t];
    #pragma unroll
    for (int o = 32; o > 0; o >>= 1) v += __shfl_down(v, o);
    if (t == 0) out[g] = v + h2b[0];
  }
}

extern "C" void kernel_launch(void* const* d_in, const int* in_sizes, int n_in,
                              void* d_out, int out_size, void* d_ws, size_t ws_size,
                              hipStream_t stream){
  const float* nodes     = (const float*)d_in[0];
  const float* node_mask = (const float*)d_in[1];
  const int*   n_node    = (const int*)  d_in[2];
  const float* i1w = (const float*)d_in[3];
  const float* i1b = (const float*)d_in[4];
  const float* i2w = (const float*)d_in[5];
  const float* i2b = (const float*)d_in[6];
  const float* j1w = (const float*)d_in[7];
  const float* j1b = (const float*)d_in[8];
  const float* j2w = (const float*)d_in[9];
  const float* j2b = (const float*)d_in[10];
  const float* h1w = (const float*)d_in[11];
  const float* h1b = (const float*)d_in[12];
  const float* h2w = (const float*)d_in[13];
  const float* h2b = (const float*)d_in[14];
  float* out = (float*)d_out;

  const int N = in_sizes[0] / 64;
  const int B = in_sizes[2];

  char* ws = (char*)d_ws;
  float* pooled = (float*)ws;                                    // B*128 f32
  size_t off = (size_t)B * 128 * 4;
  int* offs = (int*)(ws + off);                                  // B+1 ints
  off += (((size_t)(B + 1) * 4 + 255) & ~(size_t)255);
  unsigned short* wi1t = (unsigned short*)(ws + off);            // 8192
  unsigned short* wj1t = wi1t + 8192;                            // 8192
  unsigned short* wi2t = wj1t + 8192;                            // 16384
  unsigned short* wj2t = wi2t + 16384;                           // 16384

  hipMemsetAsync(pooled, 0, (size_t)B * 128 * 4, stream);
  scan_kernel<<<1, 256, 0, stream>>>(n_node, offs, B);
  prep_weights<<<192, 256, 0, stream>>>(i1w, j1w, i2w, j2w, wi1t, wj1t, wi2t, wj2t);

  int nblk = (N + 63) / 64;
  fused_node_kernel<<<nblk, 256, 0, stream>>>(nodes, node_mask, wi1t, wj1t, wi2t, wj2t,
                                              i1b, i2b, j1b, j2b, offs, pooled, N, B);
  head_kernel<<<B, 128, 0, stream>>>(pooled, h1w, h1b, h2w, h2b, out);
}